// Round 10
// baseline (256.283 us; speedup 1.0000x reference)
//
#include <hip/hip_runtime.h>
#include <hip/hip_bf16.h>

#define D 256
#define BDST 128          // dsts per bucket (dst >> 7)
#define CAP 2560          // LDS CSR capacity (bucket mean 2046, max ~2250)
#define TILE 6144         // edges per fill tile (6/thread @ 1024 threads)
#define YR 136            // padded LDS row stride (shorts) for gemm C-tile

typedef __attribute__((ext_vector_type(8))) short short8;
typedef __attribute__((ext_vector_type(4))) float f32x4;

static __device__ __forceinline__ unsigned short f2bf(float f) {
    union { float f; unsigned u; } u; u.f = f;
    unsigned r = u.u + 0x7FFF + ((u.u >> 16) & 1);   // RNE
    return (unsigned short)(r >> 16);
}

static __device__ __forceinline__ float bf2f(unsigned short b) {
    union { unsigned u; float f; } u; u.u = ((unsigned)b) << 16;
    return u.f;
}

// pack 2 f32 -> 2 bf16 (RNE) in one HW op
static __device__ __forceinline__ unsigned cvtpk(float a, float b) {
    unsigned r;
    asm("v_cvt_pk_bf16_f32 %0, %1, %2" : "=v"(r) : "v"(a), "v"(b));
    return r;
}

// K1: blocks 0..31 build wF (fragment-major B operands, 4 frags/block);
//     blocks 32..  per-bucket edge histogram (LDS-aggregated).
__global__ __launch_bounds__(256) void prep_kernel(
    const float* __restrict__ W, unsigned short* __restrict__ wF,
    const int* __restrict__ edst, int* __restrict__ gcount,
    int n_edges, int nb) {
    int tid = threadIdx.x;
    if (blockIdx.x < 32) {
        int fid = blockIdx.x * 4 + (tid >> 6);   // 0..127
        int lane = tid & 63;
        int kt = fid >> 4, nt = fid & 15;
        int col = nt * 16 + (lane & 15);
        int k0 = kt * 32 + (lane >> 4) * 8;
        unsigned short frag[8];
#pragma unroll
        for (int j = 0; j < 8; ++j) frag[j] = f2bf(W[(k0 + j) * D + col]);
        *(short8*)(wF + ((size_t)fid * 64 + lane) * 8) = *(short8*)frag;
    } else {
        __shared__ int h[1024];
        for (int j = tid; j < nb; j += 256) h[j] = 0;
        __syncthreads();
        int i = (blockIdx.x - 32) * 256 + tid;
        int stride = (gridDim.x - 32) * 256;
        for (; i < n_edges; i += stride) atomicAdd(&h[edst[i] >> 7], 1);
        __syncthreads();
        for (int j = tid; j < nb; j += 256) {
            int v = h[j];
            if (v) atomicAdd(&gcount[j], v);
        }
    }
}

// K2: block-aggregated multisplit. Each block redundantly computes the global
// bucket-offset scan from gcount in LDS (kills the separate scan kernel);
// claims are RELATIVE via atomicAdd on zero-initialized cursor.
__global__ __launch_bounds__(1024) void fill_ms_kernel(
    const int* __restrict__ esrc, const int* __restrict__ edst,
    const float* __restrict__ eval, const int* __restrict__ gcount,
    int* __restrict__ cursor, int2* __restrict__ binned,
    int n_edges, int nb) {
    __shared__ int lhist[1024];
    __shared__ int lscan[1024];
    __shared__ int lbase[1024];
    __shared__ int lcur[1024];

    int tid = threadIdx.x;

    // local exclusive scan of gcount -> per-thread register goff
    int gc = (tid < nb) ? gcount[tid] : 0;
    lscan[tid] = gc;
    __syncthreads();
    for (int off = 1; off < 1024; off <<= 1) {
        int v = (tid >= off) ? lscan[tid - off] : 0;
        __syncthreads();
        lscan[tid] += v;
        __syncthreads();
    }
    int goff = lscan[tid] - gc;      // global bucket base (own bucket tid)

    int tb = blockIdx.x * TILE;
    int m = n_edges - tb; if (m > TILE) m = TILE;

    int src[6], dst[6]; float val[6];
#pragma unroll
    for (int j = 0; j < 6; ++j) {
        int i = tid + j * 1024;
        if (i < m) { src[j] = esrc[tb + i]; dst[j] = edst[tb + i]; val[j] = eval[tb + i]; }
    }

    for (int j = tid; j < nb; j += 1024) lhist[j] = 0;
    __syncthreads();                  // also covers lscan reuse below
#pragma unroll
    for (int j = 0; j < 6; ++j)
        if (tid + j * 1024 < m) atomicAdd(&lhist[dst[j] >> 7], 1);
    __syncthreads();

    int c = (tid < nb) ? lhist[tid] : 0;
    lscan[tid] = c;
    __syncthreads();
    for (int off = 1; off < 1024; off <<= 1) {
        int v = (tid >= off) ? lscan[tid - off] : 0;
        __syncthreads();
        lscan[tid] += v;
        __syncthreads();
    }
    if (tid < nb) {
        int lofs = lscan[tid] - c;
        int g = c ? atomicAdd(&cursor[tid], c) : 0;   // RELATIVE claim
        lbase[tid] = goff + g - lofs;
        lcur[tid] = lofs;
    }
    __syncthreads();

#pragma unroll
    for (int j = 0; j < 6; ++j) {
        if (tid + j * 1024 < m) {
            int d = dst[j];
            int b = d >> 7;
            int pos = atomicAdd(&lcur[b], 1);
            binned[lbase[b] + pos] =
                make_int2(src[j] | ((d & (BDST - 1)) << 20), __float_as_int(val[j]));
        }
    }
}

// K3: y = bf16(x @ W). Wave = 32 rows (2 row-groups SHARING each B-frag load
// -> wF L2 traffic halved). nt-phase split (cols 0-127 / 128-255) keeps acc
// at 64 VGPR; each phase staged in LDS, stored as coalesced 16B chunks.
__global__ __launch_bounds__(256, 3) void gemm_kernel(
    const float* __restrict__ x, const unsigned short* __restrict__ wF,
    unsigned short* __restrict__ y, int n_nodes) {
    __shared__ unsigned short ytile[128 * YR];   // 34.8 KB

    const int tid  = threadIdx.x;
    const int lane = tid & 63;
    const int wave = tid >> 6;
    const int rsel = lane & 15;
    const int koff = (lane >> 4) * 8;
    const int brow = blockIdx.x * 128;
    const int wrow = brow + wave * 32;
    // no early return: kernel has barriers; OOB rows clamp, stores guarded

    short8 a[2][8];
#pragma unroll
    for (int rg = 0; rg < 2; ++rg) {
        int row = wrow + rg * 16 + rsel;
        int rowc = row < n_nodes ? row : n_nodes - 1;
        const float* xp = x + (size_t)rowc * D + koff;
#pragma unroll
        for (int kt = 0; kt < 8; ++kt) {
            f32x4 lo = *(const f32x4*)(xp + kt * 32);
            f32x4 hi = *(const f32x4*)(xp + kt * 32 + 4);
            union { unsigned u[4]; short8 s; } pk;
            pk.u[0] = cvtpk(lo[0], lo[1]);
            pk.u[1] = cvtpk(lo[2], lo[3]);
            pk.u[2] = cvtpk(hi[0], hi[1]);
            pk.u[3] = cvtpk(hi[2], hi[3]);
            a[rg][kt] = pk.s;
        }
    }

    const short8* wf = (const short8*)wF;
#pragma unroll
    for (int ph = 0; ph < 2; ++ph) {
        f32x4 acc[2][8];
#pragma unroll
        for (int rg = 0; rg < 2; ++rg)
#pragma unroll
            for (int n = 0; n < 8; ++n) acc[rg][n] = (f32x4){0.f, 0.f, 0.f, 0.f};

#pragma unroll
        for (int kt = 0; kt < 8; ++kt) {
#pragma unroll
            for (int n = 0; n < 8; ++n) {
                short8 bfr = wf[(kt * 16 + ph * 8 + n) * 64 + lane];
                acc[0][n] = __builtin_amdgcn_mfma_f32_16x16x32_bf16(a[0][kt], bfr, acc[0][n], 0, 0, 0);
                acc[1][n] = __builtin_amdgcn_mfma_f32_16x16x32_bf16(a[1][kt], bfr, acc[1][n], 0, 0, 0);
            }
        }

        // C/D: local col = n*16 + rsel, local row = wave*32 + rg*16 + (lane>>4)*4 + i
#pragma unroll
        for (int rg = 0; rg < 2; ++rg) {
            int lrow0 = wave * 32 + rg * 16 + (lane >> 4) * 4;
#pragma unroll
            for (int n = 0; n < 8; ++n) {
                int lcol = n * 16 + rsel;
#pragma unroll
                for (int i = 0; i < 4; ++i)
                    ytile[(lrow0 + i) * YR + lcol] = f2bf(acc[rg][n][i]);
            }
        }
        __syncthreads();

        // readout: 16 threads per row cover 128 cols (256B contiguous)
#pragma unroll
        for (int it = 0; it < 8; ++it) {
            int idx = it * 256 + tid;       // 0..2047
            int r = idx >> 4;               // 0..127
            int ch = idx & 15;
            int gr = brow + r;
            if (gr < n_nodes)
                *(short8*)(y + (size_t)gr * D + ph * 128 + ch * 8) =
                    *(const short8*)(&ytile[r * YR + ch * 8]);
        }
        __syncthreads();   // protect ytile before next phase overwrites
    }
}

// K4: one block (256 thr = 8 half-waves) per bucket; computes its own bucket
// base from gcount (LDS reduce), builds exact per-dst CSR in LDS, gathers.
__global__ __launch_bounds__(256) void bucket_gather_kernel(
    const unsigned short* __restrict__ y, const int* __restrict__ gcount,
    const int2* __restrict__ binned, float* __restrict__ out,
    int n_nodes, int nb) {
    __shared__ int2 lcsr[CAP];          // 20 KB
    __shared__ int lhist[BDST];
    __shared__ int lscan[BDST];
    __shared__ int lofs[BDST];
    __shared__ int lcur[BDST];
    __shared__ int t[256];

    int b = blockIdx.x;
    int tid = threadIdx.x;

    // beg = sum(gcount[0..b)), end = beg + gcount[b]
    int partial = 0;
    for (int j = tid; j < b; j += 256) partial += gcount[j];
    t[tid] = partial;
    __syncthreads();
    for (int off = 128; off > 0; off >>= 1) {
        if (tid < off) t[tid] += t[tid + off];
        __syncthreads();
    }
    int beg = t[0];
    int end = beg + gcount[b];
    int cnt = end - beg;
    int nch = cnt > 0 ? (cnt + CAP - 1) / CAP : 1;

    const int hw = tid >> 5;            // 0..7
    const int lane = tid & 31;
    const unsigned short* yl = y + lane * 8;

    for (int c = 0; c < nch; ++c) {
        int cb = beg + c * CAP;
        int ce = cb + CAP < end ? cb + CAP : end;
        int m = ce > cb ? ce - cb : 0;

        int2 ec[10];
#pragma unroll
        for (int j = 0; j < 10; ++j) {
            int i = tid + j * 256;
            if (i < m) ec[j] = binned[cb + i];
        }

        if (tid < BDST) lhist[tid] = 0;
        __syncthreads();
#pragma unroll
        for (int j = 0; j < 10; ++j)
            if (tid + j * 256 < m) atomicAdd(&lhist[(ec[j].x >> 20) & (BDST - 1)], 1);
        __syncthreads();
        if (tid < BDST) lscan[tid] = lhist[tid];
        __syncthreads();
        for (int off = 1; off < BDST; off <<= 1) {
            int v = 0;
            if (tid < BDST && tid >= off) v = lscan[tid - off];
            __syncthreads();
            if (tid < BDST) lscan[tid] += v;
            __syncthreads();
        }
        if (tid < BDST) {
            int e = lscan[tid] - lhist[tid];
            lofs[tid] = e;
            lcur[tid] = e;
        }
        __syncthreads();
#pragma unroll
        for (int j = 0; j < 10; ++j) {
            if (tid + j * 256 < m) {
                int pos = atomicAdd(&lcur[(ec[j].x >> 20) & (BDST - 1)], 1);
                lcsr[pos] = ec[j];
            }
        }
        __syncthreads();

        for (int dl = hw; dl < BDST; dl += 8) {
            int d = b * BDST + dl;
            if (d >= n_nodes) break;
            int i0 = lofs[dl];
            int i1 = lcur[dl];
            float acc[8] = {0.f, 0.f, 0.f, 0.f, 0.f, 0.f, 0.f, 0.f};
            int i = i0;
            for (; i + 4 <= i1; i += 4) {
                int2 e0 = lcsr[i];
                int2 e1 = lcsr[i + 1];
                int2 e2 = lcsr[i + 2];
                int2 e3 = lcsr[i + 3];
                short8 r0 = *(const short8*)(yl + (size_t)(e0.x & 0xFFFFF) * D);
                short8 r1 = *(const short8*)(yl + (size_t)(e1.x & 0xFFFFF) * D);
                short8 r2 = *(const short8*)(yl + (size_t)(e2.x & 0xFFFFF) * D);
                short8 r3 = *(const short8*)(yl + (size_t)(e3.x & 0xFFFFF) * D);
                float v0 = __int_as_float(e0.y), v1 = __int_as_float(e1.y);
                float v2 = __int_as_float(e2.y), v3 = __int_as_float(e3.y);
#pragma unroll
                for (int j = 0; j < 8; ++j) {
                    acc[j] += v0 * bf2f((unsigned short)r0[j]);
                    acc[j] += v1 * bf2f((unsigned short)r1[j]);
                    acc[j] += v2 * bf2f((unsigned short)r2[j]);
                    acc[j] += v3 * bf2f((unsigned short)r3[j]);
                }
            }
            for (; i < i1; ++i) {
                int2 e0 = lcsr[i];
                float v0 = __int_as_float(e0.y);
                short8 r0 = *(const short8*)(yl + (size_t)(e0.x & 0xFFFFF) * D);
#pragma unroll
                for (int j = 0; j < 8; ++j) acc[j] += v0 * bf2f((unsigned short)r0[j]);
            }
            float* op = out + (size_t)d * D + lane * 8;
            if (c == 0) {
                *(f32x4*)(op)     = (f32x4){acc[0], acc[1], acc[2], acc[3]};
                *(f32x4*)(op + 4) = (f32x4){acc[4], acc[5], acc[6], acc[7]};
            } else {                    // overflow chunk path (cold)
                f32x4 o0 = *(f32x4*)(op);
                f32x4 o1 = *(f32x4*)(op + 4);
                o0[0] += acc[0]; o0[1] += acc[1]; o0[2] += acc[2]; o0[3] += acc[3];
                o1[0] += acc[4]; o1[1] += acc[5]; o1[2] += acc[6]; o1[3] += acc[7];
                *(f32x4*)(op)     = o0;
                *(f32x4*)(op + 4) = o1;
            }
        }
        __syncthreads();
    }
}

extern "C" void kernel_launch(void* const* d_in, const int* in_sizes, int n_in,
                              void* d_out, int out_size, void* d_ws, size_t ws_size,
                              hipStream_t stream) {
    const float* x    = (const float*)d_in[0];
    const int*   esrc = (const int*)d_in[1];
    const int*   edst = (const int*)d_in[2];
    const float* eval = (const float*)d_in[3];
    const float* W    = (const float*)d_in[4];
    float* out = (float*)d_out;

    const int n_nodes = in_sizes[0] / D;     // 100000
    const int n_edges = in_sizes[1];         // 1600000
    const int nb = (n_nodes + BDST - 1) / BDST;   // 782 (must be <= 1024)

    // workspace layout (16B-aligned), ~64 MB
    char* ws = (char*)d_ws;
    unsigned short* y  = (unsigned short*)ws;  ws += (size_t)n_nodes * D * 2;   // 51.2 MB
    unsigned short* wF = (unsigned short*)ws;  ws += (size_t)D * D * 2;         // 128 KB
    int*  gcount  = (int*)ws;                  ws += 4096;                      // zeroed
    int*  cursor  = (int*)ws;                  ws += 4096;                      // zeroed (adjacent)
    int2* binned  = (int2*)ws;                 ws += (size_t)n_edges * 8;       // 12.8 MB

    hipMemsetAsync(gcount, 0, 8192, stream);   // gcount + cursor in one memset

    // K1: wF-build (32 blocks) || edge histogram (224 blocks)
    prep_kernel<<<256, 256, 0, stream>>>(W, wF, edst, gcount, n_edges, nb);

    // K2: multisplit fill (scan kernel eliminated: local scans + relative claims)
    const int ntiles = (n_edges + TILE - 1) / TILE;   // 261
    fill_ms_kernel<<<ntiles, 1024, 0, stream>>>(esrc, edst, eval, gcount, cursor,
                                                binned, n_edges, nb);

    // K3: gemm (32 rows/wave, B-frag reuse)
    gemm_kernel<<<(n_nodes + 127) / 128, 256, 0, stream>>>(x, wF, y, n_nodes);

    // K4: gather
    bucket_gather_kernel<<<nb, 256, 0, stream>>>(y, gcount, binned, out, n_nodes, nb);
}

// Round 11
// 239.916 us; speedup vs baseline: 1.0682x; 1.0682x over previous
//
#include <hip/hip_runtime.h>
#include <hip/hip_bf16.h>

#define D 256
#define BDST 128          // dsts per bucket (dst >> 7)
#define CAP 2560          // LDS CSR capacity (bucket mean 2046, max ~2250)
#define TILE 7168         // edges per fill tile (7/thread @ 1024 thr; 224 tiles <= 256 CUs)
#define YROW 264          // padded LDS row stride (shorts) for gemm C-tile

typedef __attribute__((ext_vector_type(8))) short short8;
typedef __attribute__((ext_vector_type(4))) float f32x4;

static __device__ __forceinline__ unsigned short f2bf(float f) {
    union { float f; unsigned u; } u; u.f = f;
    unsigned r = u.u + 0x7FFF + ((u.u >> 16) & 1);   // RNE
    return (unsigned short)(r >> 16);
}

static __device__ __forceinline__ float bf2f(unsigned short b) {
    union { unsigned u; float f; } u; u.u = ((unsigned)b) << 16;
    return u.f;
}

// pack 2 f32 -> 2 bf16 (RNE) in one HW op
static __device__ __forceinline__ unsigned cvtpk(float a, float b) {
    unsigned r;
    asm("v_cvt_pk_bf16_f32 %0, %1, %2" : "=v"(r) : "v"(a), "v"(b));
    return r;
}

// K1: blocks 0..31 build wF (fragment-major B operands, 4 frags/block);
//     blocks 32..  per-bucket edge histogram (LDS-aggregated).
__global__ __launch_bounds__(256) void prep_kernel(
    const float* __restrict__ W, unsigned short* __restrict__ wF,
    const int* __restrict__ edst, int* __restrict__ gcount,
    int n_edges, int nb) {
    int tid = threadIdx.x;
    if (blockIdx.x < 32) {
        int fid = blockIdx.x * 4 + (tid >> 6);   // 0..127
        int lane = tid & 63;
        int kt = fid >> 4, nt = fid & 15;
        int col = nt * 16 + (lane & 15);
        int k0 = kt * 32 + (lane >> 4) * 8;
        unsigned short frag[8];
#pragma unroll
        for (int j = 0; j < 8; ++j) frag[j] = f2bf(W[(k0 + j) * D + col]);
        *(short8*)(wF + ((size_t)fid * 64 + lane) * 8) = *(short8*)frag;
    } else {
        __shared__ int h[1024];
        for (int j = tid; j < nb; j += 256) h[j] = 0;
        __syncthreads();
        int i = (blockIdx.x - 32) * 256 + tid;
        int stride = (gridDim.x - 32) * 256;
        for (; i < n_edges; i += stride) atomicAdd(&h[edst[i] >> 7], 1);
        __syncthreads();
        for (int j = tid; j < nb; j += 256) {
            int v = h[j];
            if (v) atomicAdd(&gcount[j], v);
        }
    }
}

// K2: exclusive scan of gcount[0..nb) -> offs and cursor (nb <= 1024)
__global__ __launch_bounds__(1024) void scan_bucket_kernel(
    const int* __restrict__ gcount, int* __restrict__ offs,
    int* __restrict__ cursor, int nb) {
    __shared__ int t[1024];
    int tid = threadIdx.x;
    int c = (tid < nb) ? gcount[tid] : 0;
    t[tid] = c;
    __syncthreads();
    for (int off = 1; off < 1024; off <<= 1) {
        int v = (tid >= off) ? t[tid - off] : 0;
        __syncthreads();
        t[tid] += v;
        __syncthreads();
    }
    if (tid < nb) { int e = t[tid] - c; offs[tid] = e; cursor[tid] = e; }
}

// K3: block-aggregated multisplit: ONE global atomicAdd per (tile,bucket).
__global__ __launch_bounds__(1024) void fill_ms_kernel(
    const int* __restrict__ esrc, const int* __restrict__ edst,
    const float* __restrict__ eval, int* __restrict__ cursor,
    int2* __restrict__ binned, int n_edges, int nb) {
    __shared__ int lhist[1024];
    __shared__ int lscan[1024];
    __shared__ int lbase[1024];
    __shared__ int lcur[1024];

    int tid = threadIdx.x;
    int tb = blockIdx.x * TILE;
    int m = n_edges - tb; if (m > TILE) m = TILE;

    int src[7], dst[7]; float val[7];
#pragma unroll
    for (int j = 0; j < 7; ++j) {
        int i = tid + j * 1024;
        if (i < m) { src[j] = esrc[tb + i]; dst[j] = edst[tb + i]; val[j] = eval[tb + i]; }
    }

    for (int j = tid; j < nb; j += 1024) lhist[j] = 0;
    __syncthreads();
#pragma unroll
    for (int j = 0; j < 7; ++j)
        if (tid + j * 1024 < m) atomicAdd(&lhist[dst[j] >> 7], 1);
    __syncthreads();

    int c = (tid < nb) ? lhist[tid] : 0;
    lscan[tid] = c;
    __syncthreads();
    for (int off = 1; off < 1024; off <<= 1) {
        int v = (tid >= off) ? lscan[tid - off] : 0;
        __syncthreads();
        lscan[tid] += v;
        __syncthreads();
    }
    if (tid < nb) {
        int lofs = lscan[tid] - c;
        int gbase = c ? atomicAdd(&cursor[tid], c) : 0;   // one claim per bucket
        lbase[tid] = gbase - lofs;
        lcur[tid] = lofs;
    }
    __syncthreads();

#pragma unroll
    for (int j = 0; j < 7; ++j) {
        if (tid + j * 1024 < m) {
            int d = dst[j];
            int b = d >> 7;
            int pos = atomicAdd(&lcur[b], 1);
            binned[lbase[b] + pos] =
                make_int2(src[j] | ((d & (BDST - 1)) << 20), __float_as_int(val[j]));
        }
    }
}

// K4: y = bf16(x @ W). Wave = 16 rows x 256 cols; output staged through a
// padded LDS tile so global y-writes are coalesced 16B short8 stores.
__global__ __launch_bounds__(256) void gemm_kernel(
    const float* __restrict__ x, const unsigned short* __restrict__ wF,
    unsigned short* __restrict__ y, int n_nodes) {
    __shared__ unsigned short ytile[64 * YROW];   // 33 KB

    const int tid  = threadIdx.x;
    const int lane = tid & 63;
    const int wave = tid >> 6;
    const int rsel = lane & 15;
    const int koff = (lane >> 4) * 8;
    const int brow = blockIdx.x * 64;
    // no early return: kernel has barriers; OOB rows clamp, stores guarded

    int row = brow + wave * 16 + rsel;
    int rowc = row < n_nodes ? row : n_nodes - 1;
    const float* xp = x + (size_t)rowc * D + koff;

    short8 a[8];
#pragma unroll
    for (int kt = 0; kt < 8; ++kt) {
        f32x4 lo = *(const f32x4*)(xp + kt * 32);
        f32x4 hi = *(const f32x4*)(xp + kt * 32 + 4);
        union { unsigned u[4]; short8 s; } pk;
        pk.u[0] = cvtpk(lo[0], lo[1]);
        pk.u[1] = cvtpk(lo[2], lo[3]);
        pk.u[2] = cvtpk(hi[0], hi[1]);
        pk.u[3] = cvtpk(hi[2], hi[3]);
        a[kt] = pk.s;
    }

    f32x4 acc[16];
#pragma unroll
    for (int nt = 0; nt < 16; ++nt) acc[nt] = (f32x4){0.f, 0.f, 0.f, 0.f};

    const short8* wf = (const short8*)wF;
#pragma unroll
    for (int kt = 0; kt < 8; ++kt) {
#pragma unroll
        for (int nt = 0; nt < 16; ++nt) {
            short8 b = wf[(kt * 16 + nt) * 64 + lane];
            acc[nt] = __builtin_amdgcn_mfma_f32_16x16x32_bf16(a[kt], b, acc[nt], 0, 0, 0);
        }
    }

    // C/D layout: col = nt*16 + rsel, row(local) = wave*16 + (lane>>4)*4 + i
    int lrow0 = wave * 16 + (lane >> 4) * 4;
#pragma unroll
    for (int nt = 0; nt < 16; ++nt) {
        int ccol = nt * 16 + rsel;
#pragma unroll
        for (int i = 0; i < 4; ++i)
            ytile[(lrow0 + i) * YROW + ccol] = f2bf(acc[nt][i]);
    }
    __syncthreads();

    // readout: 8 rows per iteration, 32 threads per row, 16B per thread
#pragma unroll
    for (int it = 0; it < 8; ++it) {
        int r = it * 8 + (tid >> 5);
        int col = (tid & 31) * 8;
        int gr = brow + r;
        if (gr < n_nodes)
            *(short8*)(y + (size_t)gr * D + col) = *(const short8*)(&ytile[r * YROW + col]);
    }
}

// K5: one block (256 thr = 8 half-waves) per bucket of 128 dsts; exact
// per-dst CSR in LDS, then half-wave-per-dst gather of y rows.
// Bin-scan done by wave 0 via __shfl_up (no barrier storm).
__global__ __launch_bounds__(256) void bucket_gather_kernel(
    const unsigned short* __restrict__ y, const int* __restrict__ offs,
    const int* __restrict__ bend, const int2* __restrict__ binned,
    float* __restrict__ out, int n_nodes) {
    __shared__ int2 lcsr[CAP];          // 20 KB
    __shared__ int lhist[BDST];
    __shared__ int lofs[BDST];
    __shared__ int lcur[BDST];

    int b = blockIdx.x;
    int tid = threadIdx.x;
    int beg = offs[b];
    int end = bend[b];                  // cursor[b] after fill == bucket end
    int cnt = end - beg;
    int nch = cnt > 0 ? (cnt + CAP - 1) / CAP : 1;

    const int hw = tid >> 5;            // 0..7
    const int lane = tid & 31;
    const unsigned short* yl = y + lane * 8;

    for (int c = 0; c < nch; ++c) {
        int cb = beg + c * CAP;
        int ce = cb + CAP < end ? cb + CAP : end;
        int m = ce > cb ? ce - cb : 0;

        // register-cache this thread's edges (<= 10)
        int2 ec[10];
#pragma unroll
        for (int j = 0; j < 10; ++j) {
            int i = tid + j * 256;
            if (i < m) ec[j] = binned[cb + i];
        }

        if (tid < BDST) lhist[tid] = 0;
        __syncthreads();
#pragma unroll
        for (int j = 0; j < 10; ++j)
            if (tid + j * 256 < m) atomicAdd(&lhist[(ec[j].x >> 20) & (BDST - 1)], 1);
        __syncthreads();

        // exclusive scan of 128 bins: wave 0 only, 2 bins/lane, shfl scan
        if (tid < 64) {
            int h0 = lhist[2 * tid];
            int h1 = lhist[2 * tid + 1];
            int sl = h0 + h1;
            int incl = sl;
#pragma unroll
            for (int dd = 1; dd < 64; dd <<= 1) {
                int v = __shfl_up(incl, dd, 64);
                if (tid >= dd) incl += v;
            }
            int base = incl - sl;
            lofs[2 * tid] = base;          lcur[2 * tid] = base;
            lofs[2 * tid + 1] = base + h0; lcur[2 * tid + 1] = base + h0;
        }
        __syncthreads();

#pragma unroll
        for (int j = 0; j < 10; ++j) {
            if (tid + j * 256 < m) {
                int pos = atomicAdd(&lcur[(ec[j].x >> 20) & (BDST - 1)], 1);
                lcsr[pos] = ec[j];
            }
        }
        __syncthreads();

        for (int dl = hw; dl < BDST; dl += 8) {
            int d = b * BDST + dl;
            if (d >= n_nodes) break;
            int i0 = lofs[dl];
            int i1 = lcur[dl];
            float acc[8] = {0.f, 0.f, 0.f, 0.f, 0.f, 0.f, 0.f, 0.f};
            int i = i0;
            for (; i + 4 <= i1; i += 4) {
                int2 e0 = lcsr[i];
                int2 e1 = lcsr[i + 1];
                int2 e2 = lcsr[i + 2];
                int2 e3 = lcsr[i + 3];
                short8 r0 = *(const short8*)(yl + (size_t)(e0.x & 0xFFFFF) * D);
                short8 r1 = *(const short8*)(yl + (size_t)(e1.x & 0xFFFFF) * D);
                short8 r2 = *(const short8*)(yl + (size_t)(e2.x & 0xFFFFF) * D);
                short8 r3 = *(const short8*)(yl + (size_t)(e3.x & 0xFFFFF) * D);
                float v0 = __int_as_float(e0.y), v1 = __int_as_float(e1.y);
                float v2 = __int_as_float(e2.y), v3 = __int_as_float(e3.y);
#pragma unroll
                for (int j = 0; j < 8; ++j) {
                    acc[j] += v0 * bf2f((unsigned short)r0[j]);
                    acc[j] += v1 * bf2f((unsigned short)r1[j]);
                    acc[j] += v2 * bf2f((unsigned short)r2[j]);
                    acc[j] += v3 * bf2f((unsigned short)r3[j]);
                }
            }
            for (; i < i1; ++i) {
                int2 e0 = lcsr[i];
                float v0 = __int_as_float(e0.y);
                short8 r0 = *(const short8*)(yl + (size_t)(e0.x & 0xFFFFF) * D);
#pragma unroll
                for (int j = 0; j < 8; ++j) acc[j] += v0 * bf2f((unsigned short)r0[j]);
            }
            float* op = out + (size_t)d * D + lane * 8;
            if (c == 0) {
                *(f32x4*)(op)     = (f32x4){acc[0], acc[1], acc[2], acc[3]};
                *(f32x4*)(op + 4) = (f32x4){acc[4], acc[5], acc[6], acc[7]};
            } else {                    // overflow chunk path (cold)
                f32x4 o0 = *(f32x4*)(op);
                f32x4 o1 = *(f32x4*)(op + 4);
                o0[0] += acc[0]; o0[1] += acc[1]; o0[2] += acc[2]; o0[3] += acc[3];
                o1[0] += acc[4]; o1[1] += acc[5]; o1[2] += acc[6]; o1[3] += acc[7];
                *(f32x4*)(op)     = o0;
                *(f32x4*)(op + 4) = o1;
            }
        }
        __syncthreads();
    }
}

extern "C" void kernel_launch(void* const* d_in, const int* in_sizes, int n_in,
                              void* d_out, int out_size, void* d_ws, size_t ws_size,
                              hipStream_t stream) {
    const float* x    = (const float*)d_in[0];
    const int*   esrc = (const int*)d_in[1];
    const int*   edst = (const int*)d_in[2];
    const float* eval = (const float*)d_in[3];
    const float* W    = (const float*)d_in[4];
    float* out = (float*)d_out;

    const int n_nodes = in_sizes[0] / D;     // 100000
    const int n_edges = in_sizes[1];         // 1600000
    const int nb = (n_nodes + BDST - 1) / BDST;   // 782 (must be <= 1024)

    // workspace layout (16B-aligned), ~64 MB
    char* ws = (char*)d_ws;
    unsigned short* y  = (unsigned short*)ws;  ws += (size_t)n_nodes * D * 2;   // 51.2 MB
    unsigned short* wF = (unsigned short*)ws;  ws += (size_t)D * D * 2;         // 128 KB
    int*  gcount  = (int*)ws;                  ws += 4096;
    int*  offs    = (int*)ws;                  ws += 4096;
    int*  cursor  = (int*)ws;                  ws += 4096;
    int2* binned  = (int2*)ws;                 ws += (size_t)n_edges * 8;       // 12.8 MB

    hipMemsetAsync(gcount, 0, (size_t)nb * sizeof(int), stream);

    // K1: wF-build (32 blocks) || edge histogram (224 blocks)
    prep_kernel<<<256, 256, 0, stream>>>(W, wF, edst, gcount, n_edges, nb);

    // K2: bucket scan
    scan_bucket_kernel<<<1, 1024, 0, stream>>>(gcount, offs, cursor, nb);

    // K3: multisplit fill (224 tiles -> one tile per CU, balanced wall)
    const int ntiles = (n_edges + TILE - 1) / TILE;   // 224
    fill_ms_kernel<<<ntiles, 1024, 0, stream>>>(esrc, edst, eval, cursor, binned, n_edges, nb);

    // K4: gemm (separate kernel — own register budget)
    gemm_kernel<<<(n_nodes + 63) / 64, 256, 0, stream>>>(x, wF, y, n_nodes);

    // K5: gather
    bucket_gather_kernel<<<nb, 256, 0, stream>>>(y, offs, cursor, binned, out, n_nodes);
}

// Round 12
// 236.195 us; speedup vs baseline: 1.0850x; 1.0158x over previous
//
#include <hip/hip_runtime.h>
#include <hip/hip_bf16.h>

#define D 256
#define BDST 128          // dsts per bucket (dst >> 7)
#define CAP 2560          // LDS CSR capacity (bucket mean 2046, max ~2250)
#define TILE 7168         // edges per fill tile (7/thread @ 1024 thr; 224 tiles <= 256 CUs)
#define YROW 264          // padded LDS row stride (shorts) for gemm C-tile

typedef __attribute__((ext_vector_type(8))) short short8;
typedef __attribute__((ext_vector_type(4))) float f32x4;

static __device__ __forceinline__ unsigned short f2bf(float f) {
    union { float f; unsigned u; } u; u.f = f;
    unsigned r = u.u + 0x7FFF + ((u.u >> 16) & 1);   // RNE
    return (unsigned short)(r >> 16);
}

static __device__ __forceinline__ float bf2f(unsigned short b) {
    union { unsigned u; float f; } u; u.u = ((unsigned)b) << 16;
    return u.f;
}

// pack 2 f32 -> 2 bf16 (RNE) in one HW op
static __device__ __forceinline__ unsigned cvtpk(float a, float b) {
    unsigned r;
    asm("v_cvt_pk_bf16_f32 %0, %1, %2" : "=v"(r) : "v"(a), "v"(b));
    return r;
}

// K1: blocks 0..31 build wF (fragment-major B operands, 4 frags/block);
//     blocks 32..  per-bucket edge histogram (LDS-aggregated, int4 loads).
__global__ __launch_bounds__(256) void prep_kernel(
    const float* __restrict__ W, unsigned short* __restrict__ wF,
    const int* __restrict__ edst, int* __restrict__ gcount,
    int n_edges, int nb) {
    int tid = threadIdx.x;
    if (blockIdx.x < 32) {
        int fid = blockIdx.x * 4 + (tid >> 6);   // 0..127
        int lane = tid & 63;
        int kt = fid >> 4, nt = fid & 15;
        int col = nt * 16 + (lane & 15);
        int k0 = kt * 32 + (lane >> 4) * 8;
        unsigned short frag[8];
#pragma unroll
        for (int j = 0; j < 8; ++j) frag[j] = f2bf(W[(k0 + j) * D + col]);
        *(short8*)(wF + ((size_t)fid * 64 + lane) * 8) = *(short8*)frag;
    } else {
        __shared__ int h[1024];
        for (int j = tid; j < nb; j += 256) h[j] = 0;
        __syncthreads();
        const int4* e4 = (const int4*)edst;
        int n4 = n_edges >> 2;
        int i = (blockIdx.x - 32) * 256 + tid;
        int stride = (gridDim.x - 32) * 256;
        for (; i < n4; i += stride) {
            int4 v = e4[i];
            atomicAdd(&h[v.x >> 7], 1);
            atomicAdd(&h[v.y >> 7], 1);
            atomicAdd(&h[v.z >> 7], 1);
            atomicAdd(&h[v.w >> 7], 1);
        }
        for (i = (n4 << 2) + (blockIdx.x - 32) * 256 + tid; i < n_edges; i += stride)
            atomicAdd(&h[edst[i] >> 7], 1);
        __syncthreads();
        for (int j = tid; j < nb; j += 256) {
            int v = h[j];
            if (v) atomicAdd(&gcount[j], v);
        }
    }
}

// K2: exclusive scan of gcount[0..nb) -> offs and cursor (nb <= 1024)
__global__ __launch_bounds__(1024) void scan_bucket_kernel(
    const int* __restrict__ gcount, int* __restrict__ offs,
    int* __restrict__ cursor, int nb) {
    __shared__ int t[1024];
    int tid = threadIdx.x;
    int c = (tid < nb) ? gcount[tid] : 0;
    t[tid] = c;
    __syncthreads();
    for (int off = 1; off < 1024; off <<= 1) {
        int v = (tid >= off) ? t[tid - off] : 0;
        __syncthreads();
        t[tid] += v;
        __syncthreads();
    }
    if (tid < nb) { int e = t[tid] - c; offs[tid] = e; cursor[tid] = e; }
}

// K3: block-aggregated multisplit: ONE global atomicAdd per (tile,bucket).
// Scan via hierarchical wave-shfl (2 barriers, was 20).
__global__ __launch_bounds__(1024) void fill_ms_kernel(
    const int* __restrict__ esrc, const int* __restrict__ edst,
    const float* __restrict__ eval, int* __restrict__ cursor,
    int2* __restrict__ binned, int n_edges, int nb) {
    __shared__ int lhist[1024];
    __shared__ int lbase[1024];
    __shared__ int lcur[1024];
    __shared__ int wsum[16];

    int tid = threadIdx.x;
    int tb = blockIdx.x * TILE;
    int m = n_edges - tb; if (m > TILE) m = TILE;

    int src[7], dst[7]; float val[7];
#pragma unroll
    for (int j = 0; j < 7; ++j) {
        int i = tid + j * 1024;
        if (i < m) { src[j] = esrc[tb + i]; dst[j] = edst[tb + i]; val[j] = eval[tb + i]; }
    }

    for (int j = tid; j < nb; j += 1024) lhist[j] = 0;
    __syncthreads();
#pragma unroll
    for (int j = 0; j < 7; ++j)
        if (tid + j * 1024 < m) atomicAdd(&lhist[dst[j] >> 7], 1);
    __syncthreads();

    // hierarchical exclusive scan: 64-lane shfl scans + 16 wave-sum scan
    int c = (tid < nb) ? lhist[tid] : 0;
    int incl = c;
#pragma unroll
    for (int dd = 1; dd < 64; dd <<= 1) {
        int v = __shfl_up(incl, dd, 64);
        if ((tid & 63) >= dd) incl += v;
    }
    if ((tid & 63) == 63) wsum[tid >> 6] = incl;
    __syncthreads();
    if (tid < 16) {
        int wv = wsum[tid];
        int wincl = wv;
#pragma unroll
        for (int dd = 1; dd < 16; dd <<= 1) {
            int v = __shfl_up(wincl, dd, 16);
            if (tid >= dd) wincl += v;
        }
        wsum[tid] = wincl - wv;   // exclusive wave base
    }
    __syncthreads();
    int excl = wsum[tid >> 6] + incl - c;

    if (tid < nb) {
        int gbase = c ? atomicAdd(&cursor[tid], c) : 0;   // one claim per bucket
        lbase[tid] = gbase - excl;
        lcur[tid] = excl;
    }
    __syncthreads();

#pragma unroll
    for (int j = 0; j < 7; ++j) {
        if (tid + j * 1024 < m) {
            int d = dst[j];
            int b = d >> 7;
            int pos = atomicAdd(&lcur[b], 1);
            binned[lbase[b] + pos] =
                make_int2(src[j] | ((d & (BDST - 1)) << 20), __float_as_int(val[j]));
        }
    }
}

// K4: y = bf16(x @ W). Wave = 16 rows x 256 cols; output staged through a
// padded LDS tile so global y-writes are coalesced 16B short8 stores.
__global__ __launch_bounds__(256) void gemm_kernel(
    const float* __restrict__ x, const unsigned short* __restrict__ wF,
    unsigned short* __restrict__ y, int n_nodes) {
    __shared__ unsigned short ytile[64 * YROW];   // 33 KB

    const int tid  = threadIdx.x;
    const int lane = tid & 63;
    const int wave = tid >> 6;
    const int rsel = lane & 15;
    const int koff = (lane >> 4) * 8;
    const int brow = blockIdx.x * 64;
    // no early return: kernel has barriers; OOB rows clamp, stores guarded

    int row = brow + wave * 16 + rsel;
    int rowc = row < n_nodes ? row : n_nodes - 1;
    const float* xp = x + (size_t)rowc * D + koff;

    short8 a[8];
#pragma unroll
    for (int kt = 0; kt < 8; ++kt) {
        f32x4 lo = *(const f32x4*)(xp + kt * 32);
        f32x4 hi = *(const f32x4*)(xp + kt * 32 + 4);
        union { unsigned u[4]; short8 s; } pk;
        pk.u[0] = cvtpk(lo[0], lo[1]);
        pk.u[1] = cvtpk(lo[2], lo[3]);
        pk.u[2] = cvtpk(hi[0], hi[1]);
        pk.u[3] = cvtpk(hi[2], hi[3]);
        a[kt] = pk.s;
    }

    f32x4 acc[16];
#pragma unroll
    for (int nt = 0; nt < 16; ++nt) acc[nt] = (f32x4){0.f, 0.f, 0.f, 0.f};

    const short8* wf = (const short8*)wF;
#pragma unroll
    for (int kt = 0; kt < 8; ++kt) {
#pragma unroll
        for (int nt = 0; nt < 16; ++nt) {
            short8 b = wf[(kt * 16 + nt) * 64 + lane];
            acc[nt] = __builtin_amdgcn_mfma_f32_16x16x32_bf16(a[kt], b, acc[nt], 0, 0, 0);
        }
    }

    // C/D layout: col = nt*16 + rsel, row(local) = wave*16 + (lane>>4)*4 + i
    int lrow0 = wave * 16 + (lane >> 4) * 4;
#pragma unroll
    for (int nt = 0; nt < 16; ++nt) {
        int ccol = nt * 16 + rsel;
#pragma unroll
        for (int i = 0; i < 4; ++i)
            ytile[(lrow0 + i) * YROW + ccol] = f2bf(acc[nt][i]);
    }
    __syncthreads();

    // readout: 8 rows per iteration, 32 threads per row, 16B per thread
#pragma unroll
    for (int it = 0; it < 8; ++it) {
        int r = it * 8 + (tid >> 5);
        int col = (tid & 31) * 8;
        int gr = brow + r;
        if (gr < n_nodes)
            *(short8*)(y + (size_t)gr * D + col) = *(const short8*)(&ytile[r * YROW + col]);
    }
}

// K5: one block (256 thr = 8 half-waves) per bucket of 128 dsts; exact
// per-dst CSR in LDS, then half-wave-per-dst gather of y rows.
// Bin-scan done by wave 0 via __shfl_up (no barrier storm).
__global__ __launch_bounds__(256) void bucket_gather_kernel(
    const unsigned short* __restrict__ y, const int* __restrict__ offs,
    const int* __restrict__ bend, const int2* __restrict__ binned,
    float* __restrict__ out, int n_nodes) {
    __shared__ int2 lcsr[CAP];          // 20 KB
    __shared__ int lhist[BDST];
    __shared__ int lofs[BDST];
    __shared__ int lcur[BDST];

    int b = blockIdx.x;
    int tid = threadIdx.x;
    int beg = offs[b];
    int end = bend[b];                  // cursor[b] after fill == bucket end
    int cnt = end - beg;
    int nch = cnt > 0 ? (cnt + CAP - 1) / CAP : 1;

    const int hw = tid >> 5;            // 0..7
    const int lane = tid & 31;
    const unsigned short* yl = y + lane * 8;

    for (int c = 0; c < nch; ++c) {
        int cb = beg + c * CAP;
        int ce = cb + CAP < end ? cb + CAP : end;
        int m = ce > cb ? ce - cb : 0;

        // register-cache this thread's edges (<= 10)
        int2 ec[10];
#pragma unroll
        for (int j = 0; j < 10; ++j) {
            int i = tid + j * 256;
            if (i < m) ec[j] = binned[cb + i];
        }

        if (tid < BDST) lhist[tid] = 0;
        __syncthreads();
#pragma unroll
        for (int j = 0; j < 10; ++j)
            if (tid + j * 256 < m) atomicAdd(&lhist[(ec[j].x >> 20) & (BDST - 1)], 1);
        __syncthreads();

        // exclusive scan of 128 bins: wave 0 only, 2 bins/lane, shfl scan
        if (tid < 64) {
            int h0 = lhist[2 * tid];
            int h1 = lhist[2 * tid + 1];
            int sl = h0 + h1;
            int incl = sl;
#pragma unroll
            for (int dd = 1; dd < 64; dd <<= 1) {
                int v = __shfl_up(incl, dd, 64);
                if (tid >= dd) incl += v;
            }
            int base = incl - sl;
            lofs[2 * tid] = base;          lcur[2 * tid] = base;
            lofs[2 * tid + 1] = base + h0; lcur[2 * tid + 1] = base + h0;
        }
        __syncthreads();

#pragma unroll
        for (int j = 0; j < 10; ++j) {
            if (tid + j * 256 < m) {
                int pos = atomicAdd(&lcur[(ec[j].x >> 20) & (BDST - 1)], 1);
                lcsr[pos] = ec[j];
            }
        }
        __syncthreads();

        for (int dl = hw; dl < BDST; dl += 8) {
            int d = b * BDST + dl;
            if (d >= n_nodes) break;
            int i0 = lofs[dl];
            int i1 = lcur[dl];
            float acc[8] = {0.f, 0.f, 0.f, 0.f, 0.f, 0.f, 0.f, 0.f};
            int i = i0;
            for (; i + 4 <= i1; i += 4) {
                int2 e0 = lcsr[i];
                int2 e1 = lcsr[i + 1];
                int2 e2 = lcsr[i + 2];
                int2 e3 = lcsr[i + 3];
                short8 r0 = *(const short8*)(yl + (size_t)(e0.x & 0xFFFFF) * D);
                short8 r1 = *(const short8*)(yl + (size_t)(e1.x & 0xFFFFF) * D);
                short8 r2 = *(const short8*)(yl + (size_t)(e2.x & 0xFFFFF) * D);
                short8 r3 = *(const short8*)(yl + (size_t)(e3.x & 0xFFFFF) * D);
                float v0 = __int_as_float(e0.y), v1 = __int_as_float(e1.y);
                float v2 = __int_as_float(e2.y), v3 = __int_as_float(e3.y);
#pragma unroll
                for (int j = 0; j < 8; ++j) {
                    acc[j] += v0 * bf2f((unsigned short)r0[j]);
                    acc[j] += v1 * bf2f((unsigned short)r1[j]);
                    acc[j] += v2 * bf2f((unsigned short)r2[j]);
                    acc[j] += v3 * bf2f((unsigned short)r3[j]);
                }
            }
            for (; i < i1; ++i) {
                int2 e0 = lcsr[i];
                float v0 = __int_as_float(e0.y);
                short8 r0 = *(const short8*)(yl + (size_t)(e0.x & 0xFFFFF) * D);
#pragma unroll
                for (int j = 0; j < 8; ++j) acc[j] += v0 * bf2f((unsigned short)r0[j]);
            }
            float* op = out + (size_t)d * D + lane * 8;
            if (c == 0) {
                *(f32x4*)(op)     = (f32x4){acc[0], acc[1], acc[2], acc[3]};
                *(f32x4*)(op + 4) = (f32x4){acc[4], acc[5], acc[6], acc[7]};
            } else {                    // overflow chunk path (cold)
                f32x4 o0 = *(f32x4*)(op);
                f32x4 o1 = *(f32x4*)(op + 4);
                o0[0] += acc[0]; o0[1] += acc[1]; o0[2] += acc[2]; o0[3] += acc[3];
                o1[0] += acc[4]; o1[1] += acc[5]; o1[2] += acc[6]; o1[3] += acc[7];
                *(f32x4*)(op)     = o0;
                *(f32x4*)(op + 4) = o1;
            }
        }
        __syncthreads();
    }
}

extern "C" void kernel_launch(void* const* d_in, const int* in_sizes, int n_in,
                              void* d_out, int out_size, void* d_ws, size_t ws_size,
                              hipStream_t stream) {
    const float* x    = (const float*)d_in[0];
    const int*   esrc = (const int*)d_in[1];
    const int*   edst = (const int*)d_in[2];
    const float* eval = (const float*)d_in[3];
    const float* W    = (const float*)d_in[4];
    float* out = (float*)d_out;

    const int n_nodes = in_sizes[0] / D;     // 100000
    const int n_edges = in_sizes[1];         // 1600000
    const int nb = (n_nodes + BDST - 1) / BDST;   // 782 (must be <= 1024)

    // workspace layout (16B-aligned), ~64 MB
    char* ws = (char*)d_ws;
    unsigned short* y  = (unsigned short*)ws;  ws += (size_t)n_nodes * D * 2;   // 51.2 MB
    unsigned short* wF = (unsigned short*)ws;  ws += (size_t)D * D * 2;         // 128 KB
    int*  gcount  = (int*)ws;                  ws += 4096;
    int*  offs    = (int*)ws;                  ws += 4096;
    int*  cursor  = (int*)ws;                  ws += 4096;
    int2* binned  = (int2*)ws;                 ws += (size_t)n_edges * 8;       // 12.8 MB

    hipMemsetAsync(gcount, 0, (size_t)nb * sizeof(int), stream);

    // K1: wF-build (32 blocks) || edge histogram (224 blocks)
    prep_kernel<<<256, 256, 0, stream>>>(W, wF, edst, gcount, n_edges, nb);

    // K2: bucket scan
    scan_bucket_kernel<<<1, 1024, 0, stream>>>(gcount, offs, cursor, nb);

    // K3: multisplit fill (224 tiles -> one tile per CU, balanced wall)
    const int ntiles = (n_edges + TILE - 1) / TILE;   // 224
    fill_ms_kernel<<<ntiles, 1024, 0, stream>>>(esrc, edst, eval, cursor, binned, n_edges, nb);

    // K4: gemm (separate kernel — own register budget)
    gemm_kernel<<<(n_nodes + 63) / 64, 256, 0, stream>>>(x, wF, y, n_nodes);

    // K5: gather
    bucket_gather_kernel<<<nb, 256, 0, stream>>>(y, offs, cursor, binned, out, n_nodes);
}

// Round 13
// 229.881 us; speedup vs baseline: 1.1149x; 1.0275x over previous
//
#include <hip/hip_runtime.h>
#include <hip/hip_bf16.h>

#define D 256
#define BDST 128          // dsts per bucket (dst >> 7)
#define CAP 2560          // LDS CSR capacity (bucket mean 2046, max ~2250)
#define TILE 7168         // edges per fill tile (7/thread @ 1024 thr; 224 tiles <= 256 CUs)
#define YROW 264          // padded LDS row stride (shorts) for gemm C-tile

typedef __attribute__((ext_vector_type(8))) short short8;
typedef __attribute__((ext_vector_type(4))) float f32x4;

static __device__ __forceinline__ unsigned short f2bf(float f) {
    union { float f; unsigned u; } u; u.f = f;
    unsigned r = u.u + 0x7FFF + ((u.u >> 16) & 1);   // RNE
    return (unsigned short)(r >> 16);
}

static __device__ __forceinline__ float bf2f(unsigned short b) {
    union { unsigned u; float f; } u; u.u = ((unsigned)b) << 16;
    return u.f;
}

// pack 2 f32 -> 2 bf16 (RNE) in one HW op
static __device__ __forceinline__ unsigned cvtpk(float a, float b) {
    unsigned r;
    asm("v_cvt_pk_bf16_f32 %0, %1, %2" : "=v"(r) : "v"(a), "v"(b));
    return r;
}

// K1: blocks 0..31 build wF (fragment-major B operands, 4 frags/block);
//     blocks 32..  per-bucket edge histogram (LDS-aggregated, int4 loads).
__global__ __launch_bounds__(256) void prep_kernel(
    const float* __restrict__ W, unsigned short* __restrict__ wF,
    const int* __restrict__ edst, int* __restrict__ gcount,
    int n_edges, int nb) {
    int tid = threadIdx.x;
    if (blockIdx.x < 32) {
        int fid = blockIdx.x * 4 + (tid >> 6);   // 0..127
        int lane = tid & 63;
        int kt = fid >> 4, nt = fid & 15;
        int col = nt * 16 + (lane & 15);
        int k0 = kt * 32 + (lane >> 4) * 8;
        unsigned short frag[8];
#pragma unroll
        for (int j = 0; j < 8; ++j) frag[j] = f2bf(W[(k0 + j) * D + col]);
        *(short8*)(wF + ((size_t)fid * 64 + lane) * 8) = *(short8*)frag;
    } else {
        __shared__ int h[1024];
        for (int j = tid; j < nb; j += 256) h[j] = 0;
        __syncthreads();
        const int4* e4 = (const int4*)edst;
        int n4 = n_edges >> 2;
        int i = (blockIdx.x - 32) * 256 + tid;
        int stride = (gridDim.x - 32) * 256;
        for (; i < n4; i += stride) {
            int4 v = e4[i];
            atomicAdd(&h[v.x >> 7], 1);
            atomicAdd(&h[v.y >> 7], 1);
            atomicAdd(&h[v.z >> 7], 1);
            atomicAdd(&h[v.w >> 7], 1);
        }
        for (i = (n4 << 2) + (blockIdx.x - 32) * 256 + tid; i < n_edges; i += stride)
            atomicAdd(&h[edst[i] >> 7], 1);
        __syncthreads();
        for (int j = tid; j < nb; j += 256) {
            int v = h[j];
            if (v) atomicAdd(&gcount[j], v);
        }
    }
}

// K2: block-aggregated multisplit (scan kernel ELIMINATED): each block
// shfl-scans gcount for the global bucket bases (2 barriers), block 0
// publishes them to offs for the gather kernel; claims are RELATIVE via
// atomicAdd on zero-initialized cursor.
__global__ __launch_bounds__(1024) void fill_ms_kernel(
    const int* __restrict__ esrc, const int* __restrict__ edst,
    const float* __restrict__ eval, const int* __restrict__ gcount,
    int* __restrict__ offs, int* __restrict__ cursor,
    int2* __restrict__ binned, int n_edges, int nb) {
    __shared__ int lhist[1024];
    __shared__ int lbase[1024];
    __shared__ int lcur[1024];
    __shared__ int wsum[16];

    int tid = threadIdx.x;
    int tb = blockIdx.x * TILE;
    int m = n_edges - tb; if (m > TILE) m = TILE;

    // issue edge loads early (hide under the scans)
    int src[7], dst[7]; float val[7];
#pragma unroll
    for (int j = 0; j < 7; ++j) {
        int i = tid + j * 1024;
        if (i < m) { src[j] = esrc[tb + i]; dst[j] = edst[tb + i]; val[j] = eval[tb + i]; }
    }

    // --- scan 1: global bucket bases from gcount (hierarchical shfl) ---
    int gc = (tid < nb) ? gcount[tid] : 0;
    int gincl = gc;
#pragma unroll
    for (int dd = 1; dd < 64; dd <<= 1) {
        int v = __shfl_up(gincl, dd, 64);
        if ((tid & 63) >= dd) gincl += v;
    }
    if ((tid & 63) == 63) wsum[tid >> 6] = gincl;
    __syncthreads();
    if (tid < 16) {
        int wv = wsum[tid];
        int wincl = wv;
#pragma unroll
        for (int dd = 1; dd < 16; dd <<= 1) {
            int v = __shfl_up(wincl, dd, 16);
            if (tid >= dd) wincl += v;
        }
        wsum[tid] = wincl - wv;
    }
    __syncthreads();
    int goff = wsum[tid >> 6] + gincl - gc;   // exclusive global base, bucket=tid
    if (blockIdx.x == 0 && tid < nb) offs[tid] = goff;   // publish for gather

    for (int j = tid; j < nb; j += 1024) lhist[j] = 0;
    __syncthreads();
#pragma unroll
    for (int j = 0; j < 7; ++j)
        if (tid + j * 1024 < m) atomicAdd(&lhist[dst[j] >> 7], 1);
    __syncthreads();

    // --- scan 2: local tile histogram (hierarchical shfl) ---
    int c = (tid < nb) ? lhist[tid] : 0;
    int incl = c;
#pragma unroll
    for (int dd = 1; dd < 64; dd <<= 1) {
        int v = __shfl_up(incl, dd, 64);
        if ((tid & 63) >= dd) incl += v;
    }
    if ((tid & 63) == 63) wsum[tid >> 6] = incl;
    __syncthreads();
    if (tid < 16) {
        int wv = wsum[tid];
        int wincl = wv;
#pragma unroll
        for (int dd = 1; dd < 16; dd <<= 1) {
            int v = __shfl_up(wincl, dd, 16);
            if (tid >= dd) wincl += v;
        }
        wsum[tid] = wincl - wv;
    }
    __syncthreads();
    int excl = wsum[tid >> 6] + incl - c;

    if (tid < nb) {
        int g = c ? atomicAdd(&cursor[tid], c) : 0;   // RELATIVE claim
        lbase[tid] = goff + g - excl;
        lcur[tid] = excl;
    }
    __syncthreads();

#pragma unroll
    for (int j = 0; j < 7; ++j) {
        if (tid + j * 1024 < m) {
            int d = dst[j];
            int b = d >> 7;
            int pos = atomicAdd(&lcur[b], 1);
            binned[lbase[b] + pos] =
                make_int2(src[j] | ((d & (BDST - 1)) << 20), __float_as_int(val[j]));
        }
    }
}

// K3: y = bf16(x @ W). Wave = 16 rows x 256 cols; output staged through a
// padded LDS tile so global y-writes are coalesced 16B short8 stores.
__global__ __launch_bounds__(256) void gemm_kernel(
    const float* __restrict__ x, const unsigned short* __restrict__ wF,
    unsigned short* __restrict__ y, int n_nodes) {
    __shared__ unsigned short ytile[64 * YROW];   // 33 KB

    const int tid  = threadIdx.x;
    const int lane = tid & 63;
    const int wave = tid >> 6;
    const int rsel = lane & 15;
    const int koff = (lane >> 4) * 8;
    const int brow = blockIdx.x * 64;
    // no early return: kernel has barriers; OOB rows clamp, stores guarded

    int row = brow + wave * 16 + rsel;
    int rowc = row < n_nodes ? row : n_nodes - 1;
    const float* xp = x + (size_t)rowc * D + koff;

    short8 a[8];
#pragma unroll
    for (int kt = 0; kt < 8; ++kt) {
        f32x4 lo = *(const f32x4*)(xp + kt * 32);
        f32x4 hi = *(const f32x4*)(xp + kt * 32 + 4);
        union { unsigned u[4]; short8 s; } pk;
        pk.u[0] = cvtpk(lo[0], lo[1]);
        pk.u[1] = cvtpk(lo[2], lo[3]);
        pk.u[2] = cvtpk(hi[0], hi[1]);
        pk.u[3] = cvtpk(hi[2], hi[3]);
        a[kt] = pk.s;
    }

    f32x4 acc[16];
#pragma unroll
    for (int nt = 0; nt < 16; ++nt) acc[nt] = (f32x4){0.f, 0.f, 0.f, 0.f};

    const short8* wf = (const short8*)wF;
#pragma unroll
    for (int kt = 0; kt < 8; ++kt) {
#pragma unroll
        for (int nt = 0; nt < 16; ++nt) {
            short8 b = wf[(kt * 16 + nt) * 64 + lane];
            acc[nt] = __builtin_amdgcn_mfma_f32_16x16x32_bf16(a[kt], b, acc[nt], 0, 0, 0);
        }
    }

    // C/D layout: col = nt*16 + rsel, row(local) = wave*16 + (lane>>4)*4 + i
    int lrow0 = wave * 16 + (lane >> 4) * 4;
#pragma unroll
    for (int nt = 0; nt < 16; ++nt) {
        int ccol = nt * 16 + rsel;
#pragma unroll
        for (int i = 0; i < 4; ++i)
            ytile[(lrow0 + i) * YROW + ccol] = f2bf(acc[nt][i]);
    }
    __syncthreads();

    // readout: 8 rows per iteration, 32 threads per row, 16B per thread
#pragma unroll
    for (int it = 0; it < 8; ++it) {
        int r = it * 8 + (tid >> 5);
        int col = (tid & 31) * 8;
        int gr = brow + r;
        if (gr < n_nodes)
            *(short8*)(y + (size_t)gr * D + col) = *(const short8*)(&ytile[r * YROW + col]);
    }
}

// K4: one block (256 thr = 8 half-waves) per bucket of 128 dsts; exact
// per-dst CSR in LDS, then half-wave-per-dst gather of y rows.
// beg from offs (published by fill block 0); end = beg + gcount[b].
__global__ __launch_bounds__(256) void bucket_gather_kernel(
    const unsigned short* __restrict__ y, const int* __restrict__ offs,
    const int* __restrict__ gcount, const int2* __restrict__ binned,
    float* __restrict__ out, int n_nodes) {
    __shared__ int2 lcsr[CAP];          // 20 KB
    __shared__ int lhist[BDST];
    __shared__ int lofs[BDST];
    __shared__ int lcur[BDST];

    int b = blockIdx.x;
    int tid = threadIdx.x;
    int beg = offs[b];
    int end = beg + gcount[b];
    int cnt = end - beg;
    int nch = cnt > 0 ? (cnt + CAP - 1) / CAP : 1;

    const int hw = tid >> 5;            // 0..7
    const int lane = tid & 31;
    const unsigned short* yl = y + lane * 8;

    for (int c = 0; c < nch; ++c) {
        int cb = beg + c * CAP;
        int ce = cb + CAP < end ? cb + CAP : end;
        int m = ce > cb ? ce - cb : 0;

        // register-cache this thread's edges (<= 10)
        int2 ec[10];
#pragma unroll
        for (int j = 0; j < 10; ++j) {
            int i = tid + j * 256;
            if (i < m) ec[j] = binned[cb + i];
        }

        if (tid < BDST) lhist[tid] = 0;
        __syncthreads();
#pragma unroll
        for (int j = 0; j < 10; ++j)
            if (tid + j * 256 < m) atomicAdd(&lhist[(ec[j].x >> 20) & (BDST - 1)], 1);
        __syncthreads();

        // exclusive scan of 128 bins: wave 0 only, 2 bins/lane, shfl scan
        if (tid < 64) {
            int h0 = lhist[2 * tid];
            int h1 = lhist[2 * tid + 1];
            int sl = h0 + h1;
            int incl = sl;
#pragma unroll
            for (int dd = 1; dd < 64; dd <<= 1) {
                int v = __shfl_up(incl, dd, 64);
                if (tid >= dd) incl += v;
            }
            int base = incl - sl;
            lofs[2 * tid] = base;          lcur[2 * tid] = base;
            lofs[2 * tid + 1] = base + h0; lcur[2 * tid + 1] = base + h0;
        }
        __syncthreads();

#pragma unroll
        for (int j = 0; j < 10; ++j) {
            if (tid + j * 256 < m) {
                int pos = atomicAdd(&lcur[(ec[j].x >> 20) & (BDST - 1)], 1);
                lcsr[pos] = ec[j];
            }
        }
        __syncthreads();

        for (int dl = hw; dl < BDST; dl += 8) {
            int d = b * BDST + dl;
            if (d >= n_nodes) break;
            int i0 = lofs[dl];
            int i1 = lcur[dl];
            float acc[8] = {0.f, 0.f, 0.f, 0.f, 0.f, 0.f, 0.f, 0.f};
            int i = i0;
            for (; i + 4 <= i1; i += 4) {
                int2 e0 = lcsr[i];
                int2 e1 = lcsr[i + 1];
                int2 e2 = lcsr[i + 2];
                int2 e3 = lcsr[i + 3];
                short8 r0 = *(const short8*)(yl + (size_t)(e0.x & 0xFFFFF) * D);
                short8 r1 = *(const short8*)(yl + (size_t)(e1.x & 0xFFFFF) * D);
                short8 r2 = *(const short8*)(yl + (size_t)(e2.x & 0xFFFFF) * D);
                short8 r3 = *(const short8*)(yl + (size_t)(e3.x & 0xFFFFF) * D);
                float v0 = __int_as_float(e0.y), v1 = __int_as_float(e1.y);
                float v2 = __int_as_float(e2.y), v3 = __int_as_float(e3.y);
#pragma unroll
                for (int j = 0; j < 8; ++j) {
                    acc[j] += v0 * bf2f((unsigned short)r0[j]);
                    acc[j] += v1 * bf2f((unsigned short)r1[j]);
                    acc[j] += v2 * bf2f((unsigned short)r2[j]);
                    acc[j] += v3 * bf2f((unsigned short)r3[j]);
                }
            }
            for (; i < i1; ++i) {
                int2 e0 = lcsr[i];
                float v0 = __int_as_float(e0.y);
                short8 r0 = *(const short8*)(yl + (size_t)(e0.x & 0xFFFFF) * D);
#pragma unroll
                for (int j = 0; j < 8; ++j) acc[j] += v0 * bf2f((unsigned short)r0[j]);
            }
            float* op = out + (size_t)d * D + lane * 8;
            if (c == 0) {
                *(f32x4*)(op)     = (f32x4){acc[0], acc[1], acc[2], acc[3]};
                *(f32x4*)(op + 4) = (f32x4){acc[4], acc[5], acc[6], acc[7]};
            } else {                    // overflow chunk path (cold)
                f32x4 o0 = *(f32x4*)(op);
                f32x4 o1 = *(f32x4*)(op + 4);
                o0[0] += acc[0]; o0[1] += acc[1]; o0[2] += acc[2]; o0[3] += acc[3];
                o1[0] += acc[4]; o1[1] += acc[5]; o1[2] += acc[6]; o1[3] += acc[7];
                *(f32x4*)(op)     = o0;
                *(f32x4*)(op + 4) = o1;
            }
        }
        __syncthreads();
    }
}

extern "C" void kernel_launch(void* const* d_in, const int* in_sizes, int n_in,
                              void* d_out, int out_size, void* d_ws, size_t ws_size,
                              hipStream_t stream) {
    const float* x    = (const float*)d_in[0];
    const int*   esrc = (const int*)d_in[1];
    const int*   edst = (const int*)d_in[2];
    const float* eval = (const float*)d_in[3];
    const float* W    = (const float*)d_in[4];
    float* out = (float*)d_out;

    const int n_nodes = in_sizes[0] / D;     // 100000
    const int n_edges = in_sizes[1];         // 1600000
    const int nb = (n_nodes + BDST - 1) / BDST;   // 782 (must be <= 1024)

    // workspace layout (16B-aligned), ~64 MB
    char* ws = (char*)d_ws;
    unsigned short* y  = (unsigned short*)ws;  ws += (size_t)n_nodes * D * 2;   // 51.2 MB
    unsigned short* wF = (unsigned short*)ws;  ws += (size_t)D * D * 2;         // 128 KB
    int*  gcount  = (int*)ws;                  ws += 4096;                      // zeroed
    int*  cursor  = (int*)ws;                  ws += 4096;                      // zeroed (adjacent)
    int*  offs    = (int*)ws;                  ws += 4096;                      // written by fill blk 0
    int2* binned  = (int2*)ws;                 ws += (size_t)n_edges * 8;       // 12.8 MB

    hipMemsetAsync(gcount, 0, 8192, stream);   // gcount + cursor in one memset

    // K1: wF-build (32 blocks) || edge histogram (224 blocks)
    prep_kernel<<<256, 256, 0, stream>>>(W, wF, edst, gcount, n_edges, nb);

    // K2: multisplit fill (scan fused in; block 0 publishes offs)
    const int ntiles = (n_edges + TILE - 1) / TILE;   // 224
    fill_ms_kernel<<<ntiles, 1024, 0, stream>>>(esrc, edst, eval, gcount, offs,
                                                cursor, binned, n_edges, nb);

    // K3: gemm (separate kernel — own register budget)
    gemm_kernel<<<(n_nodes + 63) / 64, 256, 0, stream>>>(x, wF, y, n_nodes);

    // K4: gather
    bucket_gather_kernel<<<nb, 256, 0, stream>>>(y, offs, gcount, binned, out, n_nodes);
}